// Round 6
// baseline (283.744 us; speedup 1.0000x reference)
//
#include <hip/hip_runtime.h>
#include <hip/hip_bf16.h>

#define BATCH 256
#define NODE 256
#define FDIM 64
#define DIM 64
#define TK 20
#define BN 65536

typedef const float* fpc;

// ---------------- K1: top-20 cosine graph + emb scalars + u_i/u_j precompute ----------------
__global__ void k_graph(fpc emb, fpc att_em_i, fpc att_em_j, fpc lin_w, fpc att_i, fpc att_j,
                        int* __restrict__ topk, float* __restrict__ emi, float* __restrict__ emj,
                        float* __restrict__ u_i, float* __restrict__ u_j){
  const int t = threadIdx.x;
  if (blockIdx.x == 256){
    // u_i = lin_w @ att_i ; u_j = lin_w @ att_j   (64 floats each)
    if (t < 64){
      float s = 0.f;
      for (int c = 0; c < 64; ++c) s = fmaf(lin_w[t*64 + c], att_i[c], s);
      u_i[t] = s;
    } else if (t < 128){
      const int f = t - 64;
      float s = 0.f;
      for (int c = 0; c < 64; ++c) s = fmaf(lin_w[f*64 + c], att_j[c], s);
      u_j[f] = s;
    }
    return;
  }
  __shared__ float s_cos[NODE];
  __shared__ float s_wi[DIM];
  const int i = blockIdx.x;
  if (t < DIM) s_wi[t] = emb[i*DIM + t];
  __syncthreads();
  float dot = 0.f, nj = 0.f, ni = 0.f;
  for (int f = 0; f < DIM; ++f){
    float wj = emb[t*DIM + f];
    float wi = s_wi[f];
    dot = fmaf(wi, wj, dot);
    nj  = fmaf(wj, wj, nj);
    ni  = fmaf(wi, wi, ni);
  }
  s_cos[t] = dot / (sqrtf(ni) * sqrtf(nj));
  __syncthreads();

  if (t < 64){
    // wave 0: 20 rounds of argmax (tie -> lower index) over 256 values
    float v0 = s_cos[t], v1 = s_cos[t+64], v2 = s_cos[t+128], v3 = s_cos[t+192];
    int taken = 0;
    for (int r = 0; r < TK; ++r){
      float bv = (taken & 1) ? -3.f : v0; int bi = t;
      float c;
      c = (taken & 2) ? -3.f : v1; if (c > bv){ bv = c; bi = t+64;  }
      c = (taken & 4) ? -3.f : v2; if (c > bv){ bv = c; bi = t+128; }
      c = (taken & 8) ? -3.f : v3; if (c > bv){ bv = c; bi = t+192; }
      for (int m = 1; m < 64; m <<= 1){
        float ov = __shfl_xor(bv, m, 64);
        int   oi = __shfl_xor(bi, m, 64);
        if (ov > bv || (ov == bv && oi < bi)){ bv = ov; bi = oi; }
      }
      if (t == 0) topk[i*TK + r] = bi;
      if ((bi & 63) == t) taken |= 1 << (bi >> 6);
    }
  } else if (t < 128){
    int d = t - 64;
    float w = s_wi[d];
    float p1 = w * att_em_i[d];
    float p2 = w * att_em_j[d];
    for (int m = 1; m < 64; m <<= 1){
      p1 += __shfl_xor(p1, m, 64);
      p2 += __shfl_xor(p2, m, 64);
    }
    if (d == 0){ emi[i] = p1; emj[i] = p2; }
  }
}

// ---------------- K2: xl = x @ lin_w (bf16 out) -- lin_w column pinned in 64 VGPRs ----------------
// __launch_bounds__(256,4): VGPR cap 128 so lw4[16] stays in registers (round-5: cap 64 caused re-loads)
__global__ void __launch_bounds__(256, 4) k_xl(fpc data, fpc lin_w, __hip_bfloat16* __restrict__ xl){
  const int t = threadIdx.x, w = t >> 6, lane = t & 63;
  float4 lw4[16];
  #pragma unroll
  for (int f4 = 0; f4 < 16; ++f4){
    lw4[f4].x = lin_w[(f4*4+0)*64 + lane];
    lw4[f4].y = lin_w[(f4*4+1)*64 + lane];
    lw4[f4].z = lin_w[(f4*4+2)*64 + lane];
    lw4[f4].w = lin_w[(f4*4+3)*64 + lane];
  }
  const int R0 = blockIdx.x*32 + w*8;        // 2048 blocks x 32 rows; 8 rows/wave
  #pragma unroll
  for (int j = 0; j < 8; ++j){
    const float4* xp = (const float4*)(data + (size_t)(R0 + j)*64);
    float a0 = 0.f, a1 = 0.f, a2 = 0.f, a3 = 0.f;
    #pragma unroll
    for (int f4 = 0; f4 < 16; ++f4){
      float4 xq = xp[f4];                    // wave-uniform -> broadcast, L1-line backed
      a0 = fmaf(xq.x, lw4[f4].x, a0);
      a1 = fmaf(xq.y, lw4[f4].y, a1);
      a2 = fmaf(xq.z, lw4[f4].z, a2);
      a3 = fmaf(xq.w, lw4[f4].w, a3);
    }
    xl[(size_t)(R0 + j)*64 + lane] = __float2bfloat16((a0 + a1) + (a2 + a3));
  }
}

// ---------------- K2b: aip/ajp -- quad-per-row, coalesced, width-4 reduce ----------------
__global__ void __launch_bounds__(256) k_scal(fpc data, const float* __restrict__ u_i,
                       const float* __restrict__ u_j, fpc emi, fpc emj,
                       float* __restrict__ aip, float* __restrict__ ajp){
  __shared__ float4 s_ui[16], s_uj[16];
  const int t = threadIdx.x;
  if (t < 16)      s_ui[t]      = ((const float4*)u_i)[t];
  else if (t < 32) s_uj[t - 16] = ((const float4*)u_j)[t - 16];
  __syncthreads();
  const int g = blockIdx.x*256 + t;          // 1024 blocks: g in [0, 262144)
  const int r = g >> 2, q = g & 3;           // 4 lanes per row, coalesced
  const float4* d4 = (const float4*)data + (size_t)r*16 + q*4;
  float p1 = 0.f, p2 = 0.f;
  #pragma unroll
  for (int i = 0; i < 4; ++i){
    float4 d = d4[i];
    float4 ui = s_ui[q*4 + i], uj = s_uj[q*4 + i];
    p1 = fmaf(d.x, ui.x, fmaf(d.y, ui.y, fmaf(d.z, ui.z, fmaf(d.w, ui.w, p1))));
    p2 = fmaf(d.x, uj.x, fmaf(d.y, uj.y, fmaf(d.z, uj.z, fmaf(d.w, uj.w, p2))));
  }
  p1 += __shfl_xor(p1, 1, 64); p1 += __shfl_xor(p1, 2, 64);
  p2 += __shfl_xor(p2, 1, 64); p2 += __shfl_xor(p2, 2, 64);
  if (q == 0)      aip[r] = p1 + emi[r & 255];
  else if (q == 1) ajp[r] = p2 + emj[r & 255];
}

// ---------------- K3: wave-per-node edge softmax + bf16 gather aggregation ----------------
__global__ void __launch_bounds__(256) k_attn_agg(const int* __restrict__ topk,
                         const __hip_bfloat16* __restrict__ xl,
                         fpc aip, fpc ajp, fpc gnn_bias, float* __restrict__ agg){
  __shared__ float s_alpha[4][32];
  __shared__ int   s_src[4][32];
  const int t = threadIdx.x, w = t >> 6, lane = t & 63;
  const int v = blockIdx.x*4 + w;            // dst node in [0, BN)
  const int i = v & 255, b = v >> 8;
  float lg = -1e30f; int sl = 0;
  if (lane < 21){
    sl = (lane < 20) ? topk[i*TK + lane] : i;
    if (lane == 20 || sl != i){              // remove_self_loops, keep appended loop
      float l = aip[v] + ajp[b*NODE + sl];
      lg = (l >= 0.f) ? l : 0.2f*l;          // leaky_relu(0.2)
    }
  }
  // valid lanes are 0..20 only -> width-32 reductions suffice
  float m = lg;
  for (int s = 1; s < 32; s <<= 1) m = fmaxf(m, __shfl_xor(m, s, 32));
  float e = (lg > -1e29f) ? __expf(lg - m) : 0.f;
  float den = e;
  for (int s = 1; s < 32; s <<= 1) den += __shfl_xor(den, s, 32);
  if (lane < 21){ s_alpha[w][lane] = e / den; s_src[w][lane] = b*NODE + sl; }
  // same-wave LDS RAW: in-order per wave
  float acc = gnn_bias[lane];
  #pragma unroll
  for (int k = 0; k < 21; ++k)
    acc = fmaf(s_alpha[w][k], __bfloat162float(xl[(size_t)s_src[w][k]*64 + lane]), acc);
  agg[(size_t)v*64 + lane] = acc;
}

// ---------------- K3b: per-channel sum / sumsq over [BN, 64] ----------------
__global__ void __launch_bounds__(256) k_stats(const float* __restrict__ src,
                                               float* __restrict__ sums, float* __restrict__ sqs){
  const int t = threadIdx.x, w = t >> 6, lane = t & 63;
  const int rbase = blockIdx.x*64 + w*16;
  float s = 0.f, q = 0.f;
  #pragma unroll 4
  for (int j = 0; j < 16; ++j){
    float x = src[(size_t)(rbase + j)*64 + lane];
    s += x; q = fmaf(x, x, q);
  }
  __shared__ float ps[4][64], pq[4][64];
  ps[w][lane] = s; pq[w][lane] = q;
  __syncthreads();
  if (t < 64){
    atomicAdd(&sums[t], ps[0][t] + ps[1][t] + ps[2][t] + ps[3][t]);
    atomicAdd(&sqs[t],  pq[0][t] + pq[1][t] + pq[2][t] + pq[3][t]);
  }
}

// ---------------- K4: bn1 finalize + ReLU (in place) + bn2 partial stats ----------------
__global__ void __launch_bounds__(256) k_bn1_apply(float* __restrict__ agg, fpc emb, fpc g1, fpc be1,
                          const float* __restrict__ bn1s, const float* __restrict__ bn1q,
                          float* __restrict__ bn2s, float* __restrict__ bn2q){
  const int t = threadIdx.x, w = t >> 6, lane = t & 63;
  const float mean = bn1s[lane] * (1.f/BN);
  const float var  = bn1q[lane] * (1.f/BN) - mean*mean;
  const float sc   = g1[lane] * rsqrtf(var + 1e-5f);
  const float sh   = be1[lane] - mean*sc;
  const int rbase = blockIdx.x*64 + w*16;
  float ys = 0.f, yq = 0.f;
  #pragma unroll 4
  for (int j = 0; j < 16; ++j){
    const int r = rbase + j;
    float x = agg[(size_t)r*64 + lane];
    float g = fmaxf(fmaf(x, sc, sh), 0.f);
    agg[(size_t)r*64 + lane] = g;            // gnn_out in place
    float y = g * emb[(r & 255)*64 + lane];
    ys += y; yq = fmaf(y, y, yq);
  }
  __shared__ float ps[4][64], pq[4][64];
  ps[w][lane] = ys; pq[w][lane] = yq;
  __syncthreads();
  if (t < 64){
    atomicAdd(&bn2s[t], ps[0][t] + ps[1][t] + ps[2][t] + ps[3][t]);
    atomicAdd(&bn2q[t], pq[0][t] + pq[1][t] + pq[2][t] + pq[3][t]);
  }
}

// ---------------- K5: split-K encoder GEMM, no LDS: gnn rows wave-broadcast ----------------
// grid (64 kt, 8 bt); wave handles 8 rows x 64 cols over a 256-wide K slice.
__global__ void __launch_bounds__(256) k_enc(const float* __restrict__ gnn, fpc enc_w,
                                             float* __restrict__ part){
  const int t = threadIdx.x, w = t >> 6, c = t & 63;
  const int kt = blockIdx.x, bt = blockIdx.y;
  const int kbase = kt*256;
  const int r0 = bt*32 + w*8;
  float a[8] = {0.f,0.f,0.f,0.f,0.f,0.f,0.f,0.f};
  for (int k = 0; k < 256; k += 4){
    float e0 = enc_w[(size_t)(kbase + k + 0)*64 + c];
    float e1 = enc_w[(size_t)(kbase + k + 1)*64 + c];
    float e2 = enc_w[(size_t)(kbase + k + 2)*64 + c];
    float e3 = enc_w[(size_t)(kbase + k + 3)*64 + c];
    #pragma unroll
    for (int r = 0; r < 8; ++r){
      float4 g4 = *(const float4*)(gnn + (size_t)(r0 + r)*16384 + kbase + k);  // broadcast
      a[r] = fmaf(g4.x, e0, fmaf(g4.y, e1, fmaf(g4.z, e2, fmaf(g4.w, e3, a[r]))));
    }
  }
  #pragma unroll
  for (int r = 0; r < 8; ++r)
    part[(size_t)kt*16384 + (r0 + r)*64 + c] = a[r];
}

// ---------------- K5b: reduce split-K partials -> encoded ----------------
__global__ void __launch_bounds__(256) k_red(const float* __restrict__ part,
                                             float* __restrict__ encoded){
  const int idx = blockIdx.x*256 + threadIdx.x;   // 64 blocks x 256 = 16384
  float s = 0.f;
  #pragma unroll 8
  for (int kt = 0; kt < 64; ++kt) s += part[(size_t)kt*16384 + idx];
  encoded[idx] = s;
}

// ---------------- K6: score head (float4, 4 rows/wave, width-16 reduce) + arr in block 0 ----------------
__global__ void __launch_bounds__(256) k_score(const float* __restrict__ gnn, fpc emb, fpc g2, fpc be2,
                      const float* __restrict__ bn2s, const float* __restrict__ bn2q,
                      fpc out_w, fpc out_b,
                      const float* __restrict__ encoded, fpc enc_b, fpc arr_w, fpc arr_b,
                      float* __restrict__ out){
  const int t = threadIdx.x, w = t >> 6, lane = t & 63;
  const int qc = lane & 15, rq = lane >> 4;
  float sc[4], sh[4], ow[4];
  #pragma unroll
  for (int k = 0; k < 4; ++k){
    const int d = qc*4 + k;
    float mean = bn2s[d] * (1.f/BN);
    float var  = bn2q[d] * (1.f/BN) - mean*mean;
    sc[k] = g2[d] * rsqrtf(var + 1e-5f);
    sh[k] = be2[d] - mean*sc[k];
    ow[k] = out_w[d];
  }
  const float ob = out_b[0];
  const float4* gnn4 = (const float4*)gnn;
  const float4* emb4 = (const float4*)emb;
  const int base = blockIdx.x*32 + w*8;      // 2048 blocks x 32 rows
  #pragma unroll
  for (int it = 0; it < 2; ++it){
    const int r = base + it*4 + rq;
    float4 y4 = gnn4[(size_t)r*16 + qc];
    float4 e4 = emb4[(r & 255)*16 + qc];
    float p = 0.f, yh;
    yh = fmaxf(fmaf(y4.x*e4.x, sc[0], sh[0]), 0.f); p = fmaf(yh, ow[0], p);
    yh = fmaxf(fmaf(y4.y*e4.y, sc[1], sh[1]), 0.f); p = fmaf(yh, ow[1], p);
    yh = fmaxf(fmaf(y4.z*e4.z, sc[2], sh[2]), 0.f); p = fmaf(yh, ow[2], p);
    yh = fmaxf(fmaf(y4.w*e4.w, sc[3], sh[3]), 0.f); p = fmaf(yh, ow[3], p);
    #pragma unroll
    for (int m = 1; m < 16; m <<= 1) p += __shfl_xor(p, m, 16);
    if (qc == 0) out[r] = p + ob;
  }
  // arrangement head: block 0, thread = batch row
  if (blockIdx.x == 0){
    const int b = t;
    float o[7];
    #pragma unroll
    for (int j = 0; j < 7; ++j) o[j] = arr_b[j];
    for (int c = 0; c < 64; ++c){
      float e = encoded[b*64 + c] + enc_b[c];
      #pragma unroll
      for (int j = 0; j < 7; ++j) o[j] = fmaf(e, arr_w[c*7 + j], o[j]);
    }
    #pragma unroll
    for (int j = 0; j < 7; ++j) out[65536 + b*7 + j] = o[j];
  }
}

extern "C" void kernel_launch(void* const* d_in, const int* in_sizes, int n_in,
                              void* d_out, int out_size, void* d_ws, size_t ws_size,
                              hipStream_t stream) {
  fpc data     = (fpc)d_in[0];
  fpc emb      = (fpc)d_in[1];
  fpc lin_w    = (fpc)d_in[2];
  fpc att_i    = (fpc)d_in[3];
  fpc att_j    = (fpc)d_in[4];
  fpc att_em_i = (fpc)d_in[5];
  fpc att_em_j = (fpc)d_in[6];
  fpc gnn_bias = (fpc)d_in[7];
  fpc g1       = (fpc)d_in[8];
  fpc be1      = (fpc)d_in[9];
  fpc g2       = (fpc)d_in[10];
  fpc be2      = (fpc)d_in[11];
  fpc enc_w    = (fpc)d_in[12];
  fpc enc_b    = (fpc)d_in[13];
  fpc arr_w    = (fpc)d_in[14];
  fpc arr_b    = (fpc)d_in[15];
  fpc out_w    = (fpc)d_in[16];
  fpc out_b    = (fpc)d_in[17];

  // workspace layout (float offsets) -- ~24.6 MB of ~268 MB available
  float* fw = (float*)d_ws;
  int*   topk    = (int*)d_ws;            // [0, 5120) ints
  float* emi     = fw + 5120;             // 256
  float* emj     = fw + 5376;             // 256
  float* u_i     = fw + 5632;             // 64
  float* u_j     = fw + 5696;             // 64
  float* bn1s    = fw + 5760;             // 64  -- zero region start
  float* bn1q    = fw + 5824;             // 64
  float* bn2s    = fw + 5888;             // 64
  float* bn2q    = fw + 5952;             // 64  -- zero region end (6016)
  float* encoded = fw + 6016;             // 16384 (fully written by k_red)
  float* aip     = fw + 22400;            // 65536
  float* ajp     = fw + 87936;            // 65536
  float* agg     = fw + 153472;           // 65536*64 f32 (becomes gnn_out in place)
  __hip_bfloat16* xl = (__hip_bfloat16*)(fw + 4347776);  // 65536*64 bf16 = 8.4 MB
  float* part    = (float*)xl;            // 64*16384 f32 = 4 MB, reuses dead xl region
  float* out     = (float*)d_out;

  hipMemsetAsync((void*)bn1s, 0, 256u*sizeof(float), stream);

  k_graph    <<<257,   256, 0, stream>>>(emb, att_em_i, att_em_j, lin_w, att_i, att_j,
                                         topk, emi, emj, u_i, u_j);
  k_xl       <<<2048,  256, 0, stream>>>(data, lin_w, xl);
  k_scal     <<<1024,  256, 0, stream>>>(data, u_i, u_j, emi, emj, aip, ajp);
  k_attn_agg <<<16384, 256, 0, stream>>>(topk, xl, aip, ajp, gnn_bias, agg);
  k_stats    <<<1024,  256, 0, stream>>>(agg, bn1s, bn1q);
  k_bn1_apply<<<1024,  256, 0, stream>>>(agg, emb, g1, be1, bn1s, bn1q, bn2s, bn2q);
  k_enc      <<<dim3(64,8), 256, 0, stream>>>(agg, enc_w, part);
  k_red      <<<64,    256, 0, stream>>>(part, encoded);
  k_score    <<<2048,  256, 0, stream>>>(agg, emb, g2, be2, bn2s, bn2q, out_w, out_b,
                                         encoded, enc_b, arr_w, arr_b, out);
}